// Round 3
// baseline (1010.135 us; speedup 1.0000x reference)
//
#include <hip/hip_runtime.h>
#include <hip/hip_bf16.h>
#include <stdint.h>

#define DEV static __device__ __forceinline__

typedef __attribute__((ext_vector_type(4))) float f32x4;
typedef __attribute__((ext_vector_type(8))) short bf16x8;
typedef __attribute__((ext_vector_type(4))) float float4v;

constexpr int NBATCH = 4;
constexpr int SEQ    = 2048;
constexpr int DIM    = 2048;      // D
constexpr int NEXP   = 8;
constexpr int HEXP   = 1024;
constexpr int DSH    = 1024;
constexpr int NTOK   = NBATCH * SEQ;       // 8192
constexpr int JEXP   = NEXP * HEXP;        // 8192
constexpr int JTOT   = JEXP + DSH;         // 9216

DEV short f2bf(float f) {
  __hip_bfloat16 b = __float2bfloat16(f);
  union { __hip_bfloat16 b; short s; } u; u.b = b; return u.s;
}

// async global->LDS, 16B per lane; LDS dest is wave-uniform base + lane*16
DEV void gload16(const void* gp, const void* lp) {
  __builtin_amdgcn_global_load_lds(
      (__attribute__((address_space(1))) void*)(uintptr_t)gp,
      (__attribute__((address_space(3))) void*)(uint32_t)(uintptr_t)lp,
      16, 0, 0);
}

// ---------------- x -> bf16 ----------------
__global__ void conv_x_k(const float* __restrict__ x, short* __restrict__ xb) {
  size_t i = (size_t)blockIdx.x * blockDim.x + threadIdx.x;
  const float4v* s = reinterpret_cast<const float4v*>(x) + i * 2;
  float4v a = s[0], b = s[1];
  bf16x8 o;
  o[0] = f2bf(a.x); o[1] = f2bf(a.y); o[2] = f2bf(a.z); o[3] = f2bf(a.w);
  o[4] = f2bf(b.x); o[5] = f2bf(b.y); o[6] = f2bf(b.z); o[7] = f2bf(b.w);
  *reinterpret_cast<bf16x8*>(xb + i * 8) = o;
}

// ---------------- router: logits, softmax, aux partial sums ----------------
__global__ __launch_bounds__(256) void router_k(
    const float* __restrict__ x, const float* __restrict__ Wr,
    const float* __restrict__ br, float* __restrict__ rw,
    float* __restrict__ auxs) {
  const int wave = threadIdx.x >> 6, lane = threadIdx.x & 63;
  const int t = blockIdx.x * 4 + wave;
  const float* xr = x + (size_t)t * DIM;
  float a[NEXP];
#pragma unroll
  for (int e = 0; e < NEXP; ++e) a[e] = 0.f;
  for (int i = 0; i < DIM / 64; ++i) {
    int k = i * 64 + lane;
    float xv = xr[k];
    const float* w = Wr + (size_t)k * NEXP;
#pragma unroll
    for (int e = 0; e < NEXP; ++e) a[e] = fmaf(xv, w[e], a[e]);
  }
#pragma unroll
  for (int e = 0; e < NEXP; ++e) {
    float v = a[e];
#pragma unroll
    for (int off = 32; off > 0; off >>= 1) v += __shfl_xor(v, off, 64);
    a[e] = v + br[e];
  }
  float mx = a[0];
#pragma unroll
  for (int e = 1; e < NEXP; ++e) mx = fmaxf(mx, a[e]);
  float s = 0.f;
#pragma unroll
  for (int e = 0; e < NEXP; ++e) { a[e] = expf(a[e] - mx); s += a[e]; }
  float inv = 1.f / s;
#pragma unroll
  for (int e = 0; e < NEXP; ++e) a[e] *= inv;
  if (lane == 0) {
#pragma unroll
    for (int e = 0; e < NEXP; ++e) rw[(size_t)t * NEXP + e] = a[e];
  }
  __shared__ float blk[NEXP];
  if (threadIdx.x < NEXP) blk[threadIdx.x] = 0.f;
  __syncthreads();
  if (lane == 0) {
#pragma unroll
    for (int e = 0; e < NEXP; ++e) atomicAdd(&blk[e], a[e]);
  }
  __syncthreads();
  if (threadIdx.x < NEXP) atomicAdd(&auxs[threadIdx.x], blk[threadIdx.x]);
}

__global__ void zero_aux_k(float* auxs) {
  if (threadIdx.x < NEXP) auxs[threadIdx.x] = 0.f;
}

__global__ void fin_aux_k(const float* __restrict__ auxs, float* __restrict__ dst) {
  if (threadIdx.x == 0) {
    float s = 0.f;
    for (int e = 0; e < NEXP; ++e) {
      float u = auxs[e] / (float)NTOK - (1.0f / NEXP);
      s += u * u;
    }
    dst[0] = (s / NEXP) * 0.01f;
  }
}

// ---------- W1cat^T chunk: dst[jloc][k] (ld=DIM), j = jbase+jloc ----------
__global__ __launch_bounds__(256) void conv_w1_k(
    const float* __restrict__ W1, const float* __restrict__ Ws1,
    short* __restrict__ dst, int jbase, int jc) {
  __shared__ float tile[64][65];
  const int j0 = jbase + blockIdx.x * 64;
  const int k0 = blockIdx.y * 64;
  const int tx = threadIdx.x & 63;
  const int ty = threadIdx.x >> 6;
#pragma unroll
  for (int i = 0; i < 16; ++i) {
    int kk = ty * 16 + i;
    int j = j0 + tx, k = k0 + kk;
    float v;
    if (j < JEXP) {
      int e = j >> 10, h = j & 1023;
      v = W1[(size_t)e * DIM * HEXP + (size_t)k * HEXP + h];
    } else {
      v = Ws1[(size_t)k * DSH + (j - JEXP)];
    }
    tile[kk][tx] = v;
  }
  __syncthreads();
#pragma unroll
  for (int i = 0; i < 16; ++i) {
    int jj = ty * 16 + i;
    int jloc = j0 - jbase + jj;
    dst[(size_t)jloc * DIM + k0 + tx] = f2bf(tile[tx][jj]);
  }
}

// ---------- W2cat^T chunk: dst[d][jloc] (ld=jc); shared rows pre-scaled 0.1 ----------
__global__ __launch_bounds__(256) void conv_w2_k(
    const float* __restrict__ W2, const float* __restrict__ Ws2,
    short* __restrict__ dst, int jbase, int jc) {
  __shared__ float tile[64][65];
  const int j0 = jbase + blockIdx.x * 64;
  const int d0 = blockIdx.y * 64;
  const int tx = threadIdx.x & 63;
  const int ty = threadIdx.x >> 6;
#pragma unroll
  for (int i = 0; i < 16; ++i) {
    int jj = ty * 16 + i;
    int j = j0 + jj;
    float v;
    if (j < JEXP) {
      int e = j >> 10, h = j & 1023;
      v = W2[(size_t)e * HEXP * DIM + (size_t)h * DIM + d0 + tx];
    } else {
      v = 0.1f * Ws2[(size_t)(j - JEXP) * DIM + d0 + tx];
    }
    tile[jj][tx] = v;
  }
  __syncthreads();
#pragma unroll
  for (int i = 0; i < 16; ++i) {
    int dd = ty * 16 + i;
    dst[(size_t)(d0 + dd) * jc + (j0 - jbase) + tx] = f2bf(tile[tx][dd]);
  }
}

// ================= 256x256 deep-pipelined GEMM (8 waves, BK=32, 4-slot ring) ==========
// C[M x N] = A[M x K] * Bt[N x K]^T, bf16 in, fp32 acc.
// LDS swizzle: LDS[row][c] holds global chunk c ^ ((row>>2)&3)   (chunk = 16B)
//   -> every 16-lane group of a ds_read_b128 covers all 32 banks 2-way (free).
// MODE 0: hOut = bf16( gelu(acc + b1cat(j)) * router_w )
// MODE 1: out = acc + sum_e rw*b2 + 0.1*bs2
// MODE 2: out += acc
#define MF_ROW(MI, AV)                                                           \
  acc[MI][0] = __builtin_amdgcn_mfma_f32_16x16x32_bf16(AV, b0, acc[MI][0], 0, 0, 0); \
  acc[MI][1] = __builtin_amdgcn_mfma_f32_16x16x32_bf16(AV, b1, acc[MI][1], 0, 0, 0); \
  acc[MI][2] = __builtin_amdgcn_mfma_f32_16x16x32_bf16(AV, b2, acc[MI][2], 0, 0, 0); \
  acc[MI][3] = __builtin_amdgcn_mfma_f32_16x16x32_bf16(AV, b3, acc[MI][3], 0, 0, 0);

template <int MODE>
__global__ __launch_bounds__(512, 2) void gemm256(
    const short* __restrict__ A, const short* __restrict__ Bt, int K,
    const float* __restrict__ rw,
    const float* __restrict__ bias_a, const float* __restrict__ bias_b,
    short* __restrict__ hOut, int jbase, int jc,
    float* __restrict__ out, int nx) {
  extern __shared__ short smem[];       // 4 slots A (4*8192 shorts) + 4 slots B
  short* As = smem;
  short* Bs = smem + 32768;

  const int tid = threadIdx.x;
  const int w = tid >> 6, lane = tid & 63;
  const int wr = w >> 2, wc = w & 3;

  // bijective XCD swizzle of linear block id
  const int nwg = nx * (NTOK / 256);
  int orig = blockIdx.x;
  const int q = nwg >> 3, r = nwg & 7;
  const int xcd = orig & 7, off = orig >> 3;
  const int bid = (xcd < r ? xcd * (q + 1) : r * (q + 1) + (xcd - r) * q) + off;
  const int bx = bid % nx, by = bid / nx;
  const int m0 = by * 256, n0 = bx * 256;

  f32x4 acc[8][4] = {};

  // LDS read offsets: row*64B + ((kchunk ^ ((row>>2)&3))*16B, row = base + (lane&15)
  const int aoff = ((lane & 15) << 6) + ((((lane >> 4) ^ ((lane >> 2) & 3)) & 3) << 4);
  const char* Abase = (const char*)As + wr * 8192 + aoff;
  const char* Bbase = (const char*)Bs + wc * 4096 + aoff;

  // staging: per wave 2 issues per matrix tile of 256x32; lane covers
  // row = w*32 + {0,16} + (lane>>2), dest chunk lane&3, src chunk = (lane&3)^(lane>>4)
  // (row bits [3:2] == lane>>4 for both issues -> matches read-side XOR).
  const int srow = lane >> 2;
  const int scol = (((lane & 3) ^ (lane >> 4)) << 3);
  const short* gA0 = A + (size_t)(m0 + w * 32 + srow) * K + scol;
  const short* gB0 = Bt + (size_t)(n0 + w * 32 + srow) * K + scol;
  const size_t k16 = (size_t)16 * K;
  short* lA = As + w * 1024;
  short* lB = Bs + w * 1024;
  const int NT = K >> 5;

#define STG_A(TT) { const int sl_ = (TT) & 3; const size_t co_ = (size_t)(TT) << 5; \
    gload16(gA0 + co_, lA + sl_ * 8192);                                           \
    gload16(gA0 + k16 + co_, lA + sl_ * 8192 + 512); }
#define STG_B(TT) { const int sl_ = (TT) & 3; const size_t co_ = (size_t)(TT) << 5; \
    gload16(gB0 + co_, lB + sl_ * 8192);                                           \
    gload16(gB0 + k16 + co_, lB + sl_ * 8192 + 512); }

  // prologue: stage tiles 0,1,2 (12 vmem insts/wave); wait tile0 (first 4)
  STG_A(0); STG_B(0); STG_A(1); STG_B(1); STG_A(2); STG_B(2);
  asm volatile("s_waitcnt vmcnt(8)" ::: "memory");
  __builtin_amdgcn_s_barrier();

  for (int t = 0; t < NT; ++t) {
    const char* pa = Abase + (size_t)(t & 3) * 16384;
    const char* pb = Bbase + (size_t)(t & 3) * 16384;
    // ---- phase 0: B frags + A frags 0..3, stage A(t+3), MFMA quadrant 0 ----
    bf16x8 b0 = *(const bf16x8*)(pb);
    bf16x8 b1 = *(const bf16x8*)(pb + 1024);
    bf16x8 b2 = *(const bf16x8*)(pb + 2048);
    bf16x8 b3 = *(const bf16x8*)(pb + 3072);
    bf16x8 a0 = *(const bf16x8*)(pa);
    bf16x8 a1 = *(const bf16x8*)(pa + 1024);
    bf16x8 a2 = *(const bf16x8*)(pa + 2048);
    bf16x8 a3 = *(const bf16x8*)(pa + 3072);
    if (t + 3 < NT) STG_A(t + 3);
    __builtin_amdgcn_s_barrier();
    asm volatile("s_waitcnt lgkmcnt(0)" ::: "memory");
    __builtin_amdgcn_sched_barrier(0);
    __builtin_amdgcn_s_setprio(1);
    MF_ROW(0, a0) MF_ROW(1, a1) MF_ROW(2, a2) MF_ROW(3, a3)
    __builtin_amdgcn_s_setprio(0);
    __builtin_amdgcn_s_barrier();
    // ---- phase 1: A frags 4..7, stage B(t+3), MFMA quadrant 1 ----
    a0 = *(const bf16x8*)(pa + 4096);
    a1 = *(const bf16x8*)(pa + 5120);
    a2 = *(const bf16x8*)(pa + 6144);
    a3 = *(const bf16x8*)(pa + 7168);
    if (t + 3 < NT) STG_B(t + 3);
    __builtin_amdgcn_s_barrier();
    asm volatile("s_waitcnt lgkmcnt(0)" ::: "memory");
    __builtin_amdgcn_sched_barrier(0);
    __builtin_amdgcn_s_setprio(1);
    MF_ROW(4, a0) MF_ROW(5, a1) MF_ROW(6, a2) MF_ROW(7, a3)
    __builtin_amdgcn_s_setprio(0);
    // tile-end counted wait: guarantee tile t+1 fully landed; never 0 in steady state
    if (t <= NT - 4)      { asm volatile("s_waitcnt vmcnt(8)" ::: "memory"); }
    else if (t == NT - 3) { asm volatile("s_waitcnt vmcnt(4)" ::: "memory"); }
    else if (t == NT - 2) { asm volatile("s_waitcnt vmcnt(0)" ::: "memory"); }
    __builtin_amdgcn_s_barrier();
  }
#undef STG_A
#undef STG_B

  // ---------------- epilogue ----------------
  const int r0 = (lane >> 4) * 4;
  const int ccol = lane & 15;
#pragma unroll
  for (int m = 0; m < 8; ++m) {
#pragma unroll
    for (int i = 0; i < 4; ++i) {
      const int trow = m0 + wr * 128 + m * 16 + r0 + i;
      if (MODE == 0) {
#pragma unroll
        for (int n = 0; n < 4; ++n) {
          const int col = n0 + wc * 64 + n * 16 + ccol;
          const int j = jbase + col;
          float v = acc[m][n][i];
          float bias = (j < JEXP) ? bias_a[j] : bias_b[j - JEXP];
          float val = v + bias;
          float g = 0.5f * val * (1.0f + erff(val * 0.70710678118654752f));
          float wgt = (j < JEXP) ? rw[(size_t)trow * NEXP + (j >> 10)] : 1.0f;
          hOut[(size_t)trow * jc + col] = f2bf(g * wgt);
        }
      } else if (MODE == 1) {
        float rw8[8];
#pragma unroll
        for (int e = 0; e < 8; ++e) rw8[e] = rw[(size_t)trow * NEXP + e];
#pragma unroll
        for (int n = 0; n < 4; ++n) {
          const int col = n0 + wc * 64 + n * 16 + ccol;
          float bias = 0.1f * bias_b[col];
#pragma unroll
          for (int e = 0; e < 8; ++e) bias += rw8[e] * bias_a[(size_t)e * DIM + col];
          out[(size_t)trow * DIM + col] = acc[m][n][i] + bias;
        }
      } else {
#pragma unroll
        for (int n = 0; n < 4; ++n) {
          const int col = n0 + wc * 64 + n * 16 + ccol;
          out[(size_t)trow * DIM + col] += acc[m][n][i];
        }
      }
    }
  }
}

// ================= fallback 128x128 GEMM (round-1, proven) =================
template <int MODE>
__global__ __launch_bounds__(256) void gemm128(
    const short* __restrict__ A, const short* __restrict__ Bt, int K,
    const float* __restrict__ rw,
    const float* __restrict__ bias_a, const float* __restrict__ bias_b,
    short* __restrict__ hOut, int jbase, int jc,
    float* __restrict__ out) {
  __shared__ short As[128 * 64];
  __shared__ short Bs[128 * 64];
  const int tid = threadIdx.x;
  const int wave = tid >> 6, lane = tid & 63;
  const int wr = wave >> 1, wc = wave & 1;
  const int m0 = blockIdx.y * 128;
  const int n0 = blockIdx.x * 128;

  f32x4 acc[4][4] = {};

  const int srow = wave * 8 + (lane >> 3);
  const int scol = (((lane & 7) ^ (lane >> 3)) << 3);
  const short* gA = A + (size_t)(m0 + srow) * K + scol;
  const short* gB = Bt + (size_t)(n0 + srow) * K + scol;
  const short* lA = As + wave * 512;
  const short* lB = Bs + wave * 512;

  const int rrow = lane & 15;
  const int koff = lane >> 4;
  const int kxor = lane & 7;

  for (int kt = 0; kt < K; kt += 64) {
#pragma unroll
    for (int i = 0; i < 4; ++i) {
      gload16(gA + (size_t)i * 32 * K + kt, lA + i * 2048);
      gload16(gB + (size_t)i * 32 * K + kt, lB + i * 2048);
    }
    asm volatile("s_waitcnt vmcnt(0)" ::: "memory");
    __syncthreads();
#pragma unroll
    for (int kk = 0; kk < 2; ++kk) {
      bf16x8 af[4], bfv[4];
#pragma unroll
      for (int m = 0; m < 4; ++m) {
        int row = wr * 64 + m * 16 + rrow;
        int chunk = (kk * 4 + koff) ^ kxor;
        af[m] = *reinterpret_cast<const bf16x8*>(&As[row * 64 + chunk * 8]);
      }
#pragma unroll
      for (int n = 0; n < 4; ++n) {
        int row = wc * 64 + n * 16 + rrow;
        int chunk = (kk * 4 + koff) ^ kxor;
        bfv[n] = *reinterpret_cast<const bf16x8*>(&Bs[row * 64 + chunk * 8]);
      }
#pragma unroll
      for (int m = 0; m < 4; ++m)
#pragma unroll
        for (int n = 0; n < 4; ++n)
          acc[m][n] = __builtin_amdgcn_mfma_f32_16x16x32_bf16(af[m], bfv[n], acc[m][n], 0, 0, 0);
    }
    __syncthreads();
  }

  const int r0 = (lane >> 4) * 4;
  const int ccol = lane & 15;
#pragma unroll
  for (int m = 0; m < 4; ++m) {
#pragma unroll
    for (int n = 0; n < 4; ++n) {
      int col = n0 + wc * 64 + n * 16 + ccol;
#pragma unroll
      for (int i = 0; i < 4; ++i) {
        int t = m0 + wr * 64 + m * 16 + r0 + i;
        float v = acc[m][n][i];
        if (MODE == 0) {
          int j = jbase + col;
          float bias = (j < JEXP) ? bias_a[j] : bias_b[j - JEXP];
          float val = v + bias;
          float g = 0.5f * val * (1.0f + erff(val * 0.70710678118654752f));
          float wg = (j < JEXP) ? rw[(size_t)t * NEXP + (j >> 10)] : 1.0f;
          hOut[(size_t)t * jc + col] = f2bf(g * wg);
        } else if (MODE == 1) {
          float bias = 0.1f * bias_b[col];
#pragma unroll
          for (int e = 0; e < NEXP; ++e)
            bias += rw[(size_t)t * NEXP + e] * bias_a[(size_t)e * DIM + col];
          out[(size_t)t * DIM + col] = v + bias;
        } else {
          out[(size_t)t * DIM + col] += v;
        }
      }
    }
  }
}

extern "C" void kernel_launch(void* const* d_in, const int* in_sizes, int n_in,
                              void* d_out, int out_size, void* d_ws, size_t ws_size,
                              hipStream_t stream) {
  const float* x   = (const float*)d_in[0];
  const float* Wr  = (const float*)d_in[1];
  const float* br  = (const float*)d_in[2];
  const float* W1  = (const float*)d_in[3];
  const float* b1  = (const float*)d_in[4];
  const float* W2  = (const float*)d_in[5];
  const float* b2  = (const float*)d_in[6];
  const float* Ws1 = (const float*)d_in[7];
  const float* bs1 = (const float*)d_in[8];
  const float* Ws2 = (const float*)d_in[9];
  const float* bs2 = (const float*)d_in[10];
  float* out = (float*)d_out;

  char* wsb = (char*)d_ws;
  short* xb   = (short*)wsb;                       // 32 MiB
  float* rw   = (float*)(wsb + 33554432);          // 1 MiB region
  float* auxs = (float*)(wsb + 33816576);
  const size_t need_fixed = 33816832ull;

  // chunk width over the 9216 concat-hidden axis; multiple of 256
  const int jcands[8] = {9216, 4608, 3072, 2304, 1536, 768, 512, 256};
  int jc = 256;
  for (int ci = 0; ci < 8; ++ci) {
    if (need_fixed + (size_t)jcands[ci] * 24576ull <= ws_size) { jc = jcands[ci]; break; }
  }
  const int nc = JTOT / jc;
  short* w1t  = (short*)(wsb + need_fixed);
  short* w2t  = w1t + (size_t)jc * DIM;
  short* hbuf = w2t + (size_t)DIM * jc;

  // enable 128 KiB dynamic LDS for the big-tile GEMM; fall back if refused
  bool big = true;
  {
    auto* f0 = gemm256<0>; auto* f1 = gemm256<1>; auto* f2 = gemm256<2>;
    if (hipFuncSetAttribute(reinterpret_cast<const void*>(f0),
                            hipFuncAttributeMaxDynamicSharedMemorySize, 131072) != hipSuccess) big = false;
    if (hipFuncSetAttribute(reinterpret_cast<const void*>(f1),
                            hipFuncAttributeMaxDynamicSharedMemorySize, 131072) != hipSuccess) big = false;
    if (hipFuncSetAttribute(reinterpret_cast<const void*>(f2),
                            hipFuncAttributeMaxDynamicSharedMemorySize, 131072) != hipSuccess) big = false;
  }

  zero_aux_k<<<1, 64, 0, stream>>>(auxs);
  conv_x_k<<<(NTOK * DIM / 8) / 256, 256, 0, stream>>>(x, xb);
  router_k<<<NTOK / 4, 256, 0, stream>>>(x, Wr, br, rw, auxs);
  fin_aux_k<<<1, 64, 0, stream>>>(auxs, out + (size_t)NTOK * DIM);

  for (int c = 0; c < nc; ++c) {
    const int jbase = c * jc;
    conv_w1_k<<<dim3(jc / 64, DIM / 64), 256, 0, stream>>>(W1, Ws1, w1t, jbase, jc);
    conv_w2_k<<<dim3(jc / 64, DIM / 64), 256, 0, stream>>>(W2, Ws2, w2t, jbase, jc);
    if (big) {
      const int nx1 = jc / 256, ny = NTOK / 256;
      gemm256<0><<<nx1 * ny, 512, 131072, stream>>>(
          xb, w1t, DIM, rw, b1, bs1, hbuf, jbase, jc, nullptr, nx1);
      const int nx2 = DIM / 256;
      if (c == 0) {
        gemm256<1><<<nx2 * ny, 512, 131072, stream>>>(
            hbuf, w2t, jc, rw, b2, bs2, nullptr, 0, jc, out, nx2);
      } else {
        gemm256<2><<<nx2 * ny, 512, 131072, stream>>>(
            hbuf, w2t, jc, rw, nullptr, nullptr, nullptr, 0, jc, out, nx2);
      }
    } else {
      gemm128<0><<<dim3(jc / 128, NTOK / 128), 256, 0, stream>>>(
          xb, w1t, DIM, rw, b1, bs1, hbuf, jbase, jc, nullptr);
      if (c == 0) {
        gemm128<1><<<dim3(DIM / 128, NTOK / 128), 256, 0, stream>>>(
            hbuf, w2t, jc, rw, b2, bs2, nullptr, 0, jc, out);
      } else {
        gemm128<2><<<dim3(DIM / 128, NTOK / 128), 256, 0, stream>>>(
            hbuf, w2t, jc, rw, nullptr, nullptr, nullptr, 0, jc, out);
      }
    }
  }
}

// Round 4
// 977.168 us; speedup vs baseline: 1.0337x; 1.0337x over previous
//
#include <hip/hip_runtime.h>
#include <hip/hip_bf16.h>
#include <stdint.h>

#define DEV static __device__ __forceinline__

typedef __attribute__((ext_vector_type(4))) float f32x4;
typedef __attribute__((ext_vector_type(8))) short bf16x8;
typedef __attribute__((ext_vector_type(4))) float float4v;

constexpr int NBATCH = 4;
constexpr int SEQ    = 2048;
constexpr int DIM    = 2048;      // D
constexpr int NEXP   = 8;
constexpr int HEXP   = 1024;
constexpr int DSH    = 1024;
constexpr int NTOK   = NBATCH * SEQ;       // 8192
constexpr int JEXP   = NEXP * HEXP;        // 8192
constexpr int JTOT   = JEXP + DSH;         // 9216

DEV short f2bf(float f) {
  __hip_bfloat16 b = __float2bfloat16(f);
  union { __hip_bfloat16 b; short s; } u; u.b = b; return u.s;
}

// async global->LDS, 16B per lane; LDS dest is wave-uniform base + lane*16
DEV void gload16(const void* gp, const void* lp) {
  __builtin_amdgcn_global_load_lds(
      (__attribute__((address_space(1))) void*)(uintptr_t)gp,
      (__attribute__((address_space(3))) void*)(uint32_t)(uintptr_t)lp,
      16, 0, 0);
}

// ---------------- x -> bf16 ----------------
__global__ void conv_x_k(const float* __restrict__ x, short* __restrict__ xb) {
  size_t i = (size_t)blockIdx.x * blockDim.x + threadIdx.x;
  const float4v* s = reinterpret_cast<const float4v*>(x) + i * 2;
  float4v a = s[0], b = s[1];
  bf16x8 o;
  o[0] = f2bf(a.x); o[1] = f2bf(a.y); o[2] = f2bf(a.z); o[3] = f2bf(a.w);
  o[4] = f2bf(b.x); o[5] = f2bf(b.y); o[6] = f2bf(b.z); o[7] = f2bf(b.w);
  *reinterpret_cast<bf16x8*>(xb + i * 8) = o;
}

// ---------------- router: logits, softmax, aux partial sums ----------------
__global__ __launch_bounds__(256) void router_k(
    const float* __restrict__ x, const float* __restrict__ Wr,
    const float* __restrict__ br, float* __restrict__ rw,
    float* __restrict__ auxs) {
  const int wave = threadIdx.x >> 6, lane = threadIdx.x & 63;
  const int t = blockIdx.x * 4 + wave;
  const float* xr = x + (size_t)t * DIM;
  float a[NEXP];
#pragma unroll
  for (int e = 0; e < NEXP; ++e) a[e] = 0.f;
  for (int i = 0; i < DIM / 64; ++i) {
    int k = i * 64 + lane;
    float xv = xr[k];
    const float* w = Wr + (size_t)k * NEXP;
#pragma unroll
    for (int e = 0; e < NEXP; ++e) a[e] = fmaf(xv, w[e], a[e]);
  }
#pragma unroll
  for (int e = 0; e < NEXP; ++e) {
    float v = a[e];
#pragma unroll
    for (int off = 32; off > 0; off >>= 1) v += __shfl_xor(v, off, 64);
    a[e] = v + br[e];
  }
  float mx = a[0];
#pragma unroll
  for (int e = 1; e < NEXP; ++e) mx = fmaxf(mx, a[e]);
  float s = 0.f;
#pragma unroll
  for (int e = 0; e < NEXP; ++e) { a[e] = expf(a[e] - mx); s += a[e]; }
  float inv = 1.f / s;
#pragma unroll
  for (int e = 0; e < NEXP; ++e) a[e] *= inv;
  if (lane == 0) {
#pragma unroll
    for (int e = 0; e < NEXP; ++e) rw[(size_t)t * NEXP + e] = a[e];
  }
  __shared__ float blk[NEXP];
  if (threadIdx.x < NEXP) blk[threadIdx.x] = 0.f;
  __syncthreads();
  if (lane == 0) {
#pragma unroll
    for (int e = 0; e < NEXP; ++e) atomicAdd(&blk[e], a[e]);
  }
  __syncthreads();
  if (threadIdx.x < NEXP) atomicAdd(&auxs[threadIdx.x], blk[threadIdx.x]);
}

__global__ void zero_aux_k(float* auxs) {
  if (threadIdx.x < NEXP) auxs[threadIdx.x] = 0.f;
}

__global__ void fin_aux_k(const float* __restrict__ auxs, float* __restrict__ dst) {
  if (threadIdx.x == 0) {
    float s = 0.f;
    for (int e = 0; e < NEXP; ++e) {
      float u = auxs[e] / (float)NTOK - (1.0f / NEXP);
      s += u * u;
    }
    dst[0] = (s / NEXP) * 0.01f;
  }
}

// ---------- W1cat^T chunk: dst[jloc][k] (ld=DIM), j = jbase+jloc ----------
__global__ __launch_bounds__(256) void conv_w1_k(
    const float* __restrict__ W1, const float* __restrict__ Ws1,
    short* __restrict__ dst, int jbase, int jc) {
  __shared__ float tile[64][65];
  const int j0 = jbase + blockIdx.x * 64;
  const int k0 = blockIdx.y * 64;
  const int tx = threadIdx.x & 63;
  const int ty = threadIdx.x >> 6;
#pragma unroll
  for (int i = 0; i < 16; ++i) {
    int kk = ty * 16 + i;
    int j = j0 + tx, k = k0 + kk;
    float v;
    if (j < JEXP) {
      int e = j >> 10, h = j & 1023;
      v = W1[(size_t)e * DIM * HEXP + (size_t)k * HEXP + h];
    } else {
      v = Ws1[(size_t)k * DSH + (j - JEXP)];
    }
    tile[kk][tx] = v;
  }
  __syncthreads();
#pragma unroll
  for (int i = 0; i < 16; ++i) {
    int jj = ty * 16 + i;
    int jloc = j0 - jbase + jj;
    dst[(size_t)jloc * DIM + k0 + tx] = f2bf(tile[tx][jj]);
  }
}

// ---------- W2cat^T chunk: dst[d][jloc] (ld=jc); shared rows pre-scaled 0.1 ----------
__global__ __launch_bounds__(256) void conv_w2_k(
    const float* __restrict__ W2, const float* __restrict__ Ws2,
    short* __restrict__ dst, int jbase, int jc) {
  __shared__ float tile[64][65];
  const int j0 = jbase + blockIdx.x * 64;
  const int d0 = blockIdx.y * 64;
  const int tx = threadIdx.x & 63;
  const int ty = threadIdx.x >> 6;
#pragma unroll
  for (int i = 0; i < 16; ++i) {
    int jj = ty * 16 + i;
    int j = j0 + jj;
    float v;
    if (j < JEXP) {
      int e = j >> 10, h = j & 1023;
      v = W2[(size_t)e * HEXP * DIM + (size_t)h * DIM + d0 + tx];
    } else {
      v = 0.1f * Ws2[(size_t)(j - JEXP) * DIM + d0 + tx];
    }
    tile[jj][tx] = v;
  }
  __syncthreads();
#pragma unroll
  for (int i = 0; i < 16; ++i) {
    int dd = ty * 16 + i;
    dst[(size_t)(d0 + dd) * jc + (j0 - jbase) + tx] = f2bf(tile[tx][dd]);
  }
}

// ================= 256x256 deep-pipelined GEMM (8 waves, BK=32, 4-slot ring) ==========
// C[M x N] = A[M x K] * Bt[N x K]^T, bf16 in, fp32 acc.
// LDS swizzle (permutation form): LDS[row][p] holds global 16B-chunk p ^ ((row>>1)&3).
// Bank-quad of a read lane: q = 4*(row&1) + chunk  ->  with chunk = kchunk ^ ((row>>1)&3)
// every aligned 8-lane group of a ds_read_b128 covers all 8 bank-quads exactly once
// (previous swizzles were 2 lanes/quad per octet -> 2.8e7 conflict cycles).
// MODE 0: hOut = bf16( gelu(acc + b1cat(j)) * router_w )
// MODE 1: out = acc + sum_e rw*b2 + 0.1*bs2
// MODE 2: out += acc
#define MF_ROW(MI, AV)                                                           \
  acc[MI][0] = __builtin_amdgcn_mfma_f32_16x16x32_bf16(AV, b0, acc[MI][0], 0, 0, 0); \
  acc[MI][1] = __builtin_amdgcn_mfma_f32_16x16x32_bf16(AV, b1, acc[MI][1], 0, 0, 0); \
  acc[MI][2] = __builtin_amdgcn_mfma_f32_16x16x32_bf16(AV, b2, acc[MI][2], 0, 0, 0); \
  acc[MI][3] = __builtin_amdgcn_mfma_f32_16x16x32_bf16(AV, b3, acc[MI][3], 0, 0, 0);

template <int MODE>
__global__ __launch_bounds__(512, 2) void gemm256(
    const short* __restrict__ A, const short* __restrict__ Bt, int K,
    const float* __restrict__ rw,
    const float* __restrict__ bias_a, const float* __restrict__ bias_b,
    short* __restrict__ hOut, int jbase, int jc,
    float* __restrict__ out, int nx) {
  extern __shared__ short smem[];       // 4 slots A (4*8192 shorts) + 4 slots B
  short* As = smem;
  short* Bs = smem + 32768;

  const int tid = threadIdx.x;
  const int w = tid >> 6, lane = tid & 63;
  const int wr = w >> 2, wc = w & 3;

  // bijective XCD swizzle of linear block id
  const int nwg = nx * (NTOK / 256);
  int orig = blockIdx.x;
  const int q = nwg >> 3, r = nwg & 7;
  const int xcd = orig & 7, off = orig >> 3;
  const int bid = (xcd < r ? xcd * (q + 1) : r * (q + 1) + (xcd - r) * q) + off;
  const int bx = bid % nx, by = bid / nx;
  const int m0 = by * 256, n0 = bx * 256;

  f32x4 acc[8][4] = {};

  // LDS read offsets: row*64B + ((kchunk ^ ((row>>1)&3))*16B, row = base + (lane&15)
  const int aoff = ((lane & 15) << 6) + ((((lane >> 4) ^ ((lane >> 1) & 3)) & 3) << 4);
  const char* Abase = (const char*)As + wr * 8192 + aoff;
  const char* Bbase = (const char*)Bs + wc * 4096 + aoff;

  // staging: per wave 2 issues per matrix tile of 256x32; lane covers
  // row = w*32 + {0,16} + (lane>>2), dest chunk lane&3,
  // src chunk = (lane&3) ^ ((lane>>3)&3)   [ = destchunk ^ ((row>>1)&3) ]
  const int srow = lane >> 2;
  const int scol = (((lane & 3) ^ ((lane >> 3) & 3)) << 3);
  const short* gA0 = A + (size_t)(m0 + w * 32 + srow) * K + scol;
  const short* gB0 = Bt + (size_t)(n0 + w * 32 + srow) * K + scol;
  const size_t k16 = (size_t)16 * K;
  short* lA = As + w * 1024;
  short* lB = Bs + w * 1024;
  const int NT = K >> 5;

#define STG_A(TT) { const int sl_ = (TT) & 3; const size_t co_ = (size_t)(TT) << 5; \
    gload16(gA0 + co_, lA + sl_ * 8192);                                           \
    gload16(gA0 + k16 + co_, lA + sl_ * 8192 + 512); }
#define STG_B(TT) { const int sl_ = (TT) & 3; const size_t co_ = (size_t)(TT) << 5; \
    gload16(gB0 + co_, lB + sl_ * 8192);                                           \
    gload16(gB0 + k16 + co_, lB + sl_ * 8192 + 512); }

  // prologue: stage tiles 0,1,2 (12 vmem insts/wave); wait tile0 (first 4)
  STG_A(0); STG_B(0); STG_A(1); STG_B(1); STG_A(2); STG_B(2);
  asm volatile("s_waitcnt vmcnt(8)" ::: "memory");
  __builtin_amdgcn_s_barrier();

  for (int t = 0; t < NT; ++t) {
    const char* pa = Abase + (size_t)(t & 3) * 16384;
    const char* pb = Bbase + (size_t)(t & 3) * 16384;
    // ---- phase 0: B frags + A frags 0..3, stage A(t+3), MFMA quadrant 0 ----
    bf16x8 b0 = *(const bf16x8*)(pb);
    bf16x8 b1 = *(const bf16x8*)(pb + 1024);
    bf16x8 b2 = *(const bf16x8*)(pb + 2048);
    bf16x8 b3 = *(const bf16x8*)(pb + 3072);
    bf16x8 a0 = *(const bf16x8*)(pa);
    bf16x8 a1 = *(const bf16x8*)(pa + 1024);
    bf16x8 a2 = *(const bf16x8*)(pa + 2048);
    bf16x8 a3 = *(const bf16x8*)(pa + 3072);
    if (t + 3 < NT) STG_A(t + 3);
    __builtin_amdgcn_s_barrier();
    asm volatile("s_waitcnt lgkmcnt(0)" ::: "memory");
    __builtin_amdgcn_sched_barrier(0);
    __builtin_amdgcn_s_setprio(1);
    MF_ROW(0, a0) MF_ROW(1, a1) MF_ROW(2, a2) MF_ROW(3, a3)
    __builtin_amdgcn_s_setprio(0);
    __builtin_amdgcn_s_barrier();
    // ---- phase 1: A frags 4..7, stage B(t+3), MFMA quadrant 1 ----
    a0 = *(const bf16x8*)(pa + 4096);
    a1 = *(const bf16x8*)(pa + 5120);
    a2 = *(const bf16x8*)(pa + 6144);
    a3 = *(const bf16x8*)(pa + 7168);
    if (t + 3 < NT) STG_B(t + 3);
    __builtin_amdgcn_s_barrier();
    asm volatile("s_waitcnt lgkmcnt(0)" ::: "memory");
    __builtin_amdgcn_sched_barrier(0);
    __builtin_amdgcn_s_setprio(1);
    MF_ROW(4, a0) MF_ROW(5, a1) MF_ROW(6, a2) MF_ROW(7, a3)
    __builtin_amdgcn_s_setprio(0);
    // tile-end counted wait: guarantee tile t+1 fully landed; never 0 in steady state
    if (t <= NT - 4)      { asm volatile("s_waitcnt vmcnt(8)" ::: "memory"); }
    else if (t == NT - 3) { asm volatile("s_waitcnt vmcnt(4)" ::: "memory"); }
    else if (t == NT - 2) { asm volatile("s_waitcnt vmcnt(0)" ::: "memory"); }
    __builtin_amdgcn_s_barrier();
  }
#undef STG_A
#undef STG_B

  // ---------------- epilogue ----------------
  const int r0 = (lane >> 4) * 4;
  const int ccol = lane & 15;
#pragma unroll
  for (int m = 0; m < 8; ++m) {
#pragma unroll
    for (int i = 0; i < 4; ++i) {
      const int trow = m0 + wr * 128 + m * 16 + r0 + i;
      if (MODE == 0) {
#pragma unroll
        for (int n = 0; n < 4; ++n) {
          const int col = n0 + wc * 64 + n * 16 + ccol;
          const int j = jbase + col;
          float v = acc[m][n][i];
          float bias = (j < JEXP) ? bias_a[j] : bias_b[j - JEXP];
          float val = v + bias;
          float g = 0.5f * val * (1.0f + erff(val * 0.70710678118654752f));
          float wgt = (j < JEXP) ? rw[(size_t)trow * NEXP + (j >> 10)] : 1.0f;
          hOut[(size_t)trow * jc + col] = f2bf(g * wgt);
        }
      } else if (MODE == 1) {
        float rw8[8];
#pragma unroll
        for (int e = 0; e < 8; ++e) rw8[e] = rw[(size_t)trow * NEXP + e];
#pragma unroll
        for (int n = 0; n < 4; ++n) {
          const int col = n0 + wc * 64 + n * 16 + ccol;
          float bias = 0.1f * bias_b[col];
#pragma unroll
          for (int e = 0; e < 8; ++e) bias += rw8[e] * bias_a[(size_t)e * DIM + col];
          out[(size_t)trow * DIM + col] = acc[m][n][i] + bias;
        }
      } else {
#pragma unroll
        for (int n = 0; n < 4; ++n) {
          const int col = n0 + wc * 64 + n * 16 + ccol;
          out[(size_t)trow * DIM + col] += acc[m][n][i];
        }
      }
    }
  }
}

// ================= fallback 128x128 GEMM (round-1, proven) =================
template <int MODE>
__global__ __launch_bounds__(256) void gemm128(
    const short* __restrict__ A, const short* __restrict__ Bt, int K,
    const float* __restrict__ rw,
    const float* __restrict__ bias_a, const float* __restrict__ bias_b,
    short* __restrict__ hOut, int jbase, int jc,
    float* __restrict__ out) {
  __shared__ short As[128 * 64];
  __shared__ short Bs[128 * 64];
  const int tid = threadIdx.x;
  const int wave = tid >> 6, lane = tid & 63;
  const int wr = wave >> 1, wc = wave & 1;
  const int m0 = blockIdx.y * 128;
  const int n0 = blockIdx.x * 128;

  f32x4 acc[4][4] = {};

  const int srow = wave * 8 + (lane >> 3);
  const int scol = (((lane & 7) ^ (lane >> 3)) << 3);
  const short* gA = A + (size_t)(m0 + srow) * K + scol;
  const short* gB = Bt + (size_t)(n0 + srow) * K + scol;
  const short* lA = As + wave * 512;
  const short* lB = Bs + wave * 512;

  const int rrow = lane & 15;
  const int koff = lane >> 4;
  const int kxor = lane & 7;

  for (int kt = 0; kt < K; kt += 64) {
#pragma unroll
    for (int i = 0; i < 4; ++i) {
      gload16(gA + (size_t)i * 32 * K + kt, lA + i * 2048);
      gload16(gB + (size_t)i * 32 * K + kt, lB + i * 2048);
    }
    asm volatile("s_waitcnt vmcnt(0)" ::: "memory");
    __syncthreads();
#pragma unroll
    for (int kk = 0; kk < 2; ++kk) {
      bf16x8 af[4], bfv[4];
#pragma unroll
      for (int m = 0; m < 4; ++m) {
        int row = wr * 64 + m * 16 + rrow;
        int chunk = (kk * 4 + koff) ^ kxor;
        af[m] = *reinterpret_cast<const bf16x8*>(&As[row * 64 + chunk * 8]);
      }
#pragma unroll
      for (int n = 0; n < 4; ++n) {
        int row = wc * 64 + n * 16 + rrow;
        int chunk = (kk * 4 + koff) ^ kxor;
        bfv[n] = *reinterpret_cast<const bf16x8*>(&Bs[row * 64 + chunk * 8]);
      }
#pragma unroll
      for (int m = 0; m < 4; ++m)
#pragma unroll
        for (int n = 0; n < 4; ++n)
          acc[m][n] = __builtin_amdgcn_mfma_f32_16x16x32_bf16(af[m], bfv[n], acc[m][n], 0, 0, 0);
    }
    __syncthreads();
  }

  const int r0 = (lane >> 4) * 4;
  const int ccol = lane & 15;
#pragma unroll
  for (int m = 0; m < 4; ++m) {
#pragma unroll
    for (int n = 0; n < 4; ++n) {
      int col = n0 + wc * 64 + n * 16 + ccol;
#pragma unroll
      for (int i = 0; i < 4; ++i) {
        int t = m0 + wr * 64 + m * 16 + r0 + i;
        float v = acc[m][n][i];
        if (MODE == 0) {
          int j = jbase + col;
          float bias = (j < JEXP) ? bias_a[j] : bias_b[j - JEXP];
          float val = v + bias;
          float g = 0.5f * val * (1.0f + erff(val * 0.70710678118654752f));
          float wg = (j < JEXP) ? rw[(size_t)t * NEXP + (j >> 10)] : 1.0f;
          hOut[(size_t)t * jc + col] = f2bf(g * wg);
        } else if (MODE == 1) {
          float bias = 0.1f * bias_b[col];
#pragma unroll
          for (int e = 0; e < NEXP; ++e)
            bias += rw[(size_t)t * NEXP + e] * bias_a[(size_t)e * DIM + col];
          out[(size_t)t * DIM + col] = v + bias;
        } else {
          out[(size_t)t * DIM + col] += v;
        }
      }
    }
  }
}

extern "C" void kernel_launch(void* const* d_in, const int* in_sizes, int n_in,
                              void* d_out, int out_size, void* d_ws, size_t ws_size,
                              hipStream_t stream) {
  const float* x   = (const float*)d_in[0];
  const float* Wr  = (const float*)d_in[1];
  const float* br  = (const float*)d_in[2];
  const float* W1  = (const float*)d_in[3];
  const float* b1  = (const float*)d_in[4];
  const float* W2  = (const float*)d_in[5];
  const float* b2  = (const float*)d_in[6];
  const float* Ws1 = (const float*)d_in[7];
  const float* bs1 = (const float*)d_in[8];
  const float* Ws2 = (const float*)d_in[9];
  const float* bs2 = (const float*)d_in[10];
  float* out = (float*)d_out;

  char* wsb = (char*)d_ws;
  short* xb   = (short*)wsb;                       // 32 MiB
  float* rw   = (float*)(wsb + 33554432);          // 1 MiB region
  float* auxs = (float*)(wsb + 33816576);
  const size_t need_fixed = 33816832ull;

  // chunk width over the 9216 concat-hidden axis; multiple of 256
  const int jcands[8] = {9216, 4608, 3072, 2304, 1536, 768, 512, 256};
  int jc = 256;
  for (int ci = 0; ci < 8; ++ci) {
    if (need_fixed + (size_t)jcands[ci] * 24576ull <= ws_size) { jc = jcands[ci]; break; }
  }
  const int nc = JTOT / jc;
  short* w1t  = (short*)(wsb + need_fixed);
  short* w2t  = w1t + (size_t)jc * DIM;
  short* hbuf = w2t + (size_t)DIM * jc;

  // enable 128 KiB dynamic LDS for the big-tile GEMM; fall back if refused
  bool big = true;
  {
    auto* f0 = gemm256<0>; auto* f1 = gemm256<1>; auto* f2 = gemm256<2>;
    if (hipFuncSetAttribute(reinterpret_cast<const void*>(f0),
                            hipFuncAttributeMaxDynamicSharedMemorySize, 131072) != hipSuccess) big = false;
    if (hipFuncSetAttribute(reinterpret_cast<const void*>(f1),
                            hipFuncAttributeMaxDynamicSharedMemorySize, 131072) != hipSuccess) big = false;
    if (hipFuncSetAttribute(reinterpret_cast<const void*>(f2),
                            hipFuncAttributeMaxDynamicSharedMemorySize, 131072) != hipSuccess) big = false;
  }

  zero_aux_k<<<1, 64, 0, stream>>>(auxs);
  conv_x_k<<<(NTOK * DIM / 8) / 256, 256, 0, stream>>>(x, xb);
  router_k<<<NTOK / 4, 256, 0, stream>>>(x, Wr, br, rw, auxs);
  fin_aux_k<<<1, 64, 0, stream>>>(auxs, out + (size_t)NTOK * DIM);

  for (int c = 0; c < nc; ++c) {
    const int jbase = c * jc;
    conv_w1_k<<<dim3(jc / 64, DIM / 64), 256, 0, stream>>>(W1, Ws1, w1t, jbase, jc);
    conv_w2_k<<<dim3(jc / 64, DIM / 64), 256, 0, stream>>>(W2, Ws2, w2t, jbase, jc);
    if (big) {
      const int nx1 = jc / 256, ny = NTOK / 256;
      gemm256<0><<<nx1 * ny, 512, 131072, stream>>>(
          xb, w1t, DIM, rw, b1, bs1, hbuf, jbase, jc, nullptr, nx1);
      const int nx2 = DIM / 256;
      if (c == 0) {
        gemm256<1><<<nx2 * ny, 512, 131072, stream>>>(
            hbuf, w2t, jc, rw, b2, bs2, nullptr, 0, jc, out, nx2);
      } else {
        gemm256<2><<<nx2 * ny, 512, 131072, stream>>>(
            hbuf, w2t, jc, rw, nullptr, nullptr, nullptr, 0, jc, out, nx2);
      }
    } else {
      gemm128<0><<<dim3(jc / 128, NTOK / 128), 256, 0, stream>>>(
          xb, w1t, DIM, rw, b1, bs1, hbuf, jbase, jc, nullptr);
      if (c == 0) {
        gemm128<1><<<dim3(DIM / 128, NTOK / 128), 256, 0, stream>>>(
            hbuf, w2t, jc, rw, b2, bs2, nullptr, 0, jc, out);
      } else {
        gemm128<2><<<dim3(DIM / 128, NTOK / 128), 256, 0, stream>>>(
            hbuf, w2t, jc, rw, nullptr, nullptr, nullptr, 0, jc, out);
      }
    }
  }
}

// Round 5
// 940.180 us; speedup vs baseline: 1.0744x; 1.0393x over previous
//
#include <hip/hip_runtime.h>
#include <hip/hip_bf16.h>
#include <stdint.h>

#define DEV static __device__ __forceinline__

typedef __attribute__((ext_vector_type(4))) float f32x4;
typedef __attribute__((ext_vector_type(8))) short bf16x8;
typedef __attribute__((ext_vector_type(4))) float float4v;

constexpr int NBATCH = 4;
constexpr int SEQ    = 2048;
constexpr int DIM    = 2048;      // D
constexpr int NEXP   = 8;
constexpr int HEXP   = 1024;
constexpr int DSH    = 1024;
constexpr int NTOK   = NBATCH * SEQ;       // 8192
constexpr int JEXP   = NEXP * HEXP;        // 8192
constexpr int JTOT   = JEXP + DSH;         // 9216

DEV short f2bf(float f) {
  __hip_bfloat16 b = __float2bfloat16(f);
  union { __hip_bfloat16 b; short s; } u; u.b = b; return u.s;
}

// async global->LDS, 16B per lane; LDS dest is wave-uniform base + lane*16
DEV void gload16(const void* gp, const void* lp) {
  __builtin_amdgcn_global_load_lds(
      (__attribute__((address_space(1))) void*)(uintptr_t)gp,
      (__attribute__((address_space(3))) void*)(uint32_t)(uintptr_t)lp,
      16, 0, 0);
}

// ---------------- x -> bf16 ----------------
__global__ void conv_x_k(const float* __restrict__ x, short* __restrict__ xb) {
  size_t i = (size_t)blockIdx.x * blockDim.x + threadIdx.x;
  const float4v* s = reinterpret_cast<const float4v*>(x) + i * 2;
  float4v a = s[0], b = s[1];
  bf16x8 o;
  o[0] = f2bf(a.x); o[1] = f2bf(a.y); o[2] = f2bf(a.z); o[3] = f2bf(a.w);
  o[4] = f2bf(b.x); o[5] = f2bf(b.y); o[6] = f2bf(b.z); o[7] = f2bf(b.w);
  *reinterpret_cast<bf16x8*>(xb + i * 8) = o;
}

// ---------------- router: logits, softmax, aux partial sums ----------------
__global__ __launch_bounds__(256) void router_k(
    const float* __restrict__ x, const float* __restrict__ Wr,
    const float* __restrict__ br, float* __restrict__ rw,
    float* __restrict__ auxs) {
  const int wave = threadIdx.x >> 6, lane = threadIdx.x & 63;
  const int t = blockIdx.x * 4 + wave;
  const float* xr = x + (size_t)t * DIM;
  float a[NEXP];
#pragma unroll
  for (int e = 0; e < NEXP; ++e) a[e] = 0.f;
  for (int i = 0; i < DIM / 64; ++i) {
    int k = i * 64 + lane;
    float xv = xr[k];
    const float* w = Wr + (size_t)k * NEXP;
#pragma unroll
    for (int e = 0; e < NEXP; ++e) a[e] = fmaf(xv, w[e], a[e]);
  }
#pragma unroll
  for (int e = 0; e < NEXP; ++e) {
    float v = a[e];
#pragma unroll
    for (int off = 32; off > 0; off >>= 1) v += __shfl_xor(v, off, 64);
    a[e] = v + br[e];
  }
  float mx = a[0];
#pragma unroll
  for (int e = 1; e < NEXP; ++e) mx = fmaxf(mx, a[e]);
  float s = 0.f;
#pragma unroll
  for (int e = 0; e < NEXP; ++e) { a[e] = expf(a[e] - mx); s += a[e]; }
  float inv = 1.f / s;
#pragma unroll
  for (int e = 0; e < NEXP; ++e) a[e] *= inv;
  if (lane == 0) {
#pragma unroll
    for (int e = 0; e < NEXP; ++e) rw[(size_t)t * NEXP + e] = a[e];
  }
  __shared__ float blk[NEXP];
  if (threadIdx.x < NEXP) blk[threadIdx.x] = 0.f;
  __syncthreads();
  if (lane == 0) {
#pragma unroll
    for (int e = 0; e < NEXP; ++e) atomicAdd(&blk[e], a[e]);
  }
  __syncthreads();
  if (threadIdx.x < NEXP) atomicAdd(&auxs[threadIdx.x], blk[threadIdx.x]);
}

__global__ void zero_aux_k(float* auxs) {
  if (threadIdx.x < NEXP) auxs[threadIdx.x] = 0.f;
}

__global__ void fin_aux_k(const float* __restrict__ auxs, float* __restrict__ dst) {
  if (threadIdx.x == 0) {
    float s = 0.f;
    for (int e = 0; e < NEXP; ++e) {
      float u = auxs[e] / (float)NTOK - (1.0f / NEXP);
      s += u * u;
    }
    dst[0] = (s / NEXP) * 0.01f;
  }
}

// ---------- W1cat^T chunk: dst[jloc][k] (ld=DIM), j = jbase+jloc ----------
__global__ __launch_bounds__(256) void conv_w1_k(
    const float* __restrict__ W1, const float* __restrict__ Ws1,
    short* __restrict__ dst, int jbase, int jc) {
  __shared__ float tile[64][65];
  const int j0 = jbase + blockIdx.x * 64;
  const int k0 = blockIdx.y * 64;
  const int tx = threadIdx.x & 63;
  const int ty = threadIdx.x >> 6;
#pragma unroll
  for (int i = 0; i < 16; ++i) {
    int kk = ty * 16 + i;
    int j = j0 + tx, k = k0 + kk;
    float v;
    if (j < JEXP) {
      int e = j >> 10, h = j & 1023;
      v = W1[(size_t)e * DIM * HEXP + (size_t)k * HEXP + h];
    } else {
      v = Ws1[(size_t)k * DSH + (j - JEXP)];
    }
    tile[kk][tx] = v;
  }
  __syncthreads();
#pragma unroll
  for (int i = 0; i < 16; ++i) {
    int jj = ty * 16 + i;
    int jloc = j0 - jbase + jj;
    dst[(size_t)jloc * DIM + k0 + tx] = f2bf(tile[tx][jj]);
  }
}

// ---------- W2cat^T chunk: dst[d][jloc] (ld=jc); shared rows pre-scaled 0.1 ----------
__global__ __launch_bounds__(256) void conv_w2_k(
    const float* __restrict__ W2, const float* __restrict__ Ws2,
    short* __restrict__ dst, int jbase, int jc) {
  __shared__ float tile[64][65];
  const int j0 = jbase + blockIdx.x * 64;
  const int d0 = blockIdx.y * 64;
  const int tx = threadIdx.x & 63;
  const int ty = threadIdx.x >> 6;
#pragma unroll
  for (int i = 0; i < 16; ++i) {
    int jj = ty * 16 + i;
    int j = j0 + jj;
    float v;
    if (j < JEXP) {
      int e = j >> 10, h = j & 1023;
      v = W2[(size_t)e * HEXP * DIM + (size_t)h * DIM + d0 + tx];
    } else {
      v = 0.1f * Ws2[(size_t)(j - JEXP) * DIM + d0 + tx];
    }
    tile[jj][tx] = v;
  }
  __syncthreads();
#pragma unroll
  for (int i = 0; i < 16; ++i) {
    int dd = ty * 16 + i;
    dst[(size_t)(d0 + dd) * jc + (j0 - jbase) + tx] = f2bf(tile[tx][dd]);
  }
}

// ===== 256x256 GEMM, 8 waves, BK=32, 4-slot LDS ring, 1 barrier/tile,
// one-phase-ahead register pipeline with counted lgkmcnt (T3+T4+T5).
// LDS swizzle (permutation form, round-4, conflict-free): LDS[row][p] holds
// global 16B-chunk p ^ ((row>>1)&3).
// Per tile t:
//   ph0: a47-reads(slot t) | vmcnt(4) | BARRIER | STG_A(t+3) | lgkm(4) | MFMA set0
//   ph1: b/a03-reads(slot t+1) | STG_B(t+3) | lgkm(8) | MFMA set1 | reg-swap
// vmcnt in instruction units (2 per STG): steady outstanding = 8, drain t+1 -> 4.
// lgkm(4): drains prev-phase's 8 frag reads, leaves the 4 a47 in flight.
// lgkm(8): drains the 4 a47 reads, leaves next tile's 8 in flight.
template <int MODE>
__global__ __launch_bounds__(512, 2) void gemm256(
    const short* __restrict__ A, const short* __restrict__ Bt, int K,
    const float* __restrict__ rw,
    const float* __restrict__ bias_a, const float* __restrict__ bias_b,
    short* __restrict__ hOut, int jbase, int jc,
    float* __restrict__ out, int nx) {
  extern __shared__ short smem[];       // 4 slots A (4*8192 shorts) + 4 slots B
  short* As = smem;
  short* Bs = smem + 32768;

  const int tid = threadIdx.x;
  const int w = tid >> 6, lane = tid & 63;
  const int wr = w >> 2, wc = w & 3;

  // bijective XCD swizzle of linear block id
  const int nwg = nx * (NTOK / 256);
  int orig = blockIdx.x;
  const int q = nwg >> 3, r = nwg & 7;
  const int xcd = orig & 7, off = orig >> 3;
  const int bid = (xcd < r ? xcd * (q + 1) : r * (q + 1) + (xcd - r) * q) + off;
  const int bx = bid % nx, by = bid / nx;
  const int m0 = by * 256, n0 = bx * 256;

  f32x4 acc[8][4] = {};

  // LDS read offsets: row*64B + (kchunk ^ ((row>>1)&3))*16B, row = base + (lane&15)
  const int aoff = ((lane & 15) << 6) + ((((lane >> 4) ^ ((lane >> 1) & 3)) & 3) << 4);
  const char* Abase = (const char*)As + wr * 8192 + aoff;
  const char* Bbase = (const char*)Bs + wc * 4096 + aoff;

  // staging: row = w*32 + {0,16} + (lane>>2), dest chunk lane&3,
  // src chunk = (lane&3) ^ ((lane>>3)&3)   [ = destchunk ^ ((row>>1)&3) ]
  const int srow = lane >> 2;
  const int scol = (((lane & 3) ^ ((lane >> 3) & 3)) << 3);
  const short* gA0 = A + (size_t)(m0 + w * 32 + srow) * K + scol;
  const short* gB0 = Bt + (size_t)(n0 + w * 32 + srow) * K + scol;
  const size_t k16 = (size_t)16 * K;
  short* lA = As + w * 1024;
  short* lB = Bs + w * 1024;
  const int NT = K >> 5;

#define STG_A(TT) { const int sl_ = (TT) & 3; const size_t co_ = (size_t)(TT) << 5; \
    gload16(gA0 + co_, lA + sl_ * 8192);                                           \
    gload16(gA0 + k16 + co_, lA + sl_ * 8192 + 512); }
#define STG_B(TT) { const int sl_ = (TT) & 3; const size_t co_ = (size_t)(TT) << 5; \
    gload16(gB0 + co_, lB + sl_ * 8192);                                           \
    gload16(gB0 + k16 + co_, lB + sl_ * 8192 + 512); }

  // prologue: stage tiles 0,1,2 (12 vmem insts); drain tile 0; preload its frags
  STG_A(0); STG_B(0); STG_A(1); STG_B(1); STG_A(2); STG_B(2);
  asm volatile("s_waitcnt vmcnt(8)" ::: "memory");
  __builtin_amdgcn_s_barrier();
  __builtin_amdgcn_sched_barrier(0);

  bf16x8 bc[4], a03[4], a47[4], bn[4], a03n[4];
#pragma unroll
  for (int i = 0; i < 4; ++i) bc[i]  = *(const bf16x8*)(Bbase + i * 1024);
#pragma unroll
  for (int i = 0; i < 4; ++i) a03[i] = *(const bf16x8*)(Abase + i * 1024);

  for (int t = 0; t < NT; ++t) {
    const char* pa = Abase + (size_t)(t & 3) * 16384;
    // ---- phase 0 ----
#pragma unroll
    for (int i = 0; i < 4; ++i) a47[i] = *(const bf16x8*)(pa + 4096 + i * 1024);
    if (t <= NT - 3) { asm volatile("s_waitcnt vmcnt(4)" ::: "memory"); }
    else             { asm volatile("s_waitcnt vmcnt(0)" ::: "memory"); }
    __builtin_amdgcn_s_barrier();
    __builtin_amdgcn_sched_barrier(0);
    if (t + 3 < NT) STG_A(t + 3);
    asm volatile("s_waitcnt lgkmcnt(4)" ::: "memory");
    __builtin_amdgcn_sched_barrier(0);
    __builtin_amdgcn_s_setprio(1);
#pragma unroll
    for (int mi = 0; mi < 4; ++mi)
#pragma unroll
      for (int ni = 0; ni < 4; ++ni)
        acc[mi][ni] = __builtin_amdgcn_mfma_f32_16x16x32_bf16(a03[mi], bc[ni], acc[mi][ni], 0, 0, 0);
    __builtin_amdgcn_s_setprio(0);
    // ---- phase 1 ----
    if (t + 1 < NT) {
      const char* pan = Abase + (size_t)((t + 1) & 3) * 16384;
      const char* pbn = Bbase + (size_t)((t + 1) & 3) * 16384;
#pragma unroll
      for (int i = 0; i < 4; ++i) bn[i]   = *(const bf16x8*)(pbn + i * 1024);
#pragma unroll
      for (int i = 0; i < 4; ++i) a03n[i] = *(const bf16x8*)(pan + i * 1024);
      if (t + 3 < NT) STG_B(t + 3);
      asm volatile("s_waitcnt lgkmcnt(8)" ::: "memory");
    } else {
      asm volatile("s_waitcnt lgkmcnt(0)" ::: "memory");
    }
    __builtin_amdgcn_sched_barrier(0);
    __builtin_amdgcn_s_setprio(1);
#pragma unroll
    for (int mi = 0; mi < 4; ++mi)
#pragma unroll
      for (int ni = 0; ni < 4; ++ni)
        acc[mi + 4][ni] = __builtin_amdgcn_mfma_f32_16x16x32_bf16(a47[mi], bc[ni], acc[mi + 4][ni], 0, 0, 0);
    __builtin_amdgcn_s_setprio(0);
#pragma unroll
    for (int i = 0; i < 4; ++i) { bc[i] = bn[i]; a03[i] = a03n[i]; }
  }
#undef STG_A
#undef STG_B

  // ---------------- epilogue ----------------
  const int r0 = (lane >> 4) * 4;
  const int ccol = lane & 15;
#pragma unroll
  for (int m = 0; m < 8; ++m) {
#pragma unroll
    for (int i = 0; i < 4; ++i) {
      const int trow = m0 + wr * 128 + m * 16 + r0 + i;
      if (MODE == 0) {
#pragma unroll
        for (int n = 0; n < 4; ++n) {
          const int col = n0 + wc * 64 + n * 16 + ccol;
          const int j = jbase + col;
          float v = acc[m][n][i];
          float bias = (j < JEXP) ? bias_a[j] : bias_b[j - JEXP];
          float val = v + bias;
          float g = 0.5f * val * (1.0f + erff(val * 0.70710678118654752f));
          float wgt = (j < JEXP) ? rw[(size_t)trow * NEXP + (j >> 10)] : 1.0f;
          hOut[(size_t)trow * jc + col] = f2bf(g * wgt);
        }
      } else if (MODE == 1) {
        float rw8[8];
#pragma unroll
        for (int e = 0; e < 8; ++e) rw8[e] = rw[(size_t)trow * NEXP + e];
#pragma unroll
        for (int n = 0; n < 4; ++n) {
          const int col = n0 + wc * 64 + n * 16 + ccol;
          float bias = 0.1f * bias_b[col];
#pragma unroll
          for (int e = 0; e < 8; ++e) bias += rw8[e] * bias_a[(size_t)e * DIM + col];
          out[(size_t)trow * DIM + col] = acc[m][n][i] + bias;
        }
      } else {
#pragma unroll
        for (int n = 0; n < 4; ++n) {
          const int col = n0 + wc * 64 + n * 16 + ccol;
          out[(size_t)trow * DIM + col] += acc[m][n][i];
        }
      }
    }
  }
}

// ================= fallback 128x128 GEMM (round-1, proven) =================
template <int MODE>
__global__ __launch_bounds__(256) void gemm128(
    const short* __restrict__ A, const short* __restrict__ Bt, int K,
    const float* __restrict__ rw,
    const float* __restrict__ bias_a, const float* __restrict__ bias_b,
    short* __restrict__ hOut, int jbase, int jc,
    float* __restrict__ out) {
  __shared__ short As[128 * 64];
  __shared__ short Bs[128 * 64];
  const int tid = threadIdx.x;
  const int wave = tid >> 6, lane = tid & 63;
  const int wr = wave >> 1, wc = wave & 1;
  const int m0 = blockIdx.y * 128;
  const int n0 = blockIdx.x * 128;

  f32x4 acc[4][4] = {};

  const int srow = wave * 8 + (lane >> 3);
  const int scol = (((lane & 7) ^ (lane >> 3)) << 3);
  const short* gA = A + (size_t)(m0 + srow) * K + scol;
  const short* gB = Bt + (size_t)(n0 + srow) * K + scol;
  const short* lA = As + wave * 512;
  const short* lB = Bs + wave * 512;

  const int rrow = lane & 15;
  const int koff = lane >> 4;
  const int kxor = lane & 7;

  for (int kt = 0; kt < K; kt += 64) {
#pragma unroll
    for (int i = 0; i < 4; ++i) {
      gload16(gA + (size_t)i * 32 * K + kt, lA + i * 2048);
      gload16(gB + (size_t)i * 32 * K + kt, lB + i * 2048);
    }
    asm volatile("s_waitcnt vmcnt(0)" ::: "memory");
    __syncthreads();
#pragma unroll
    for (int kk = 0; kk < 2; ++kk) {
      bf16x8 af[4], bfv[4];
#pragma unroll
      for (int m = 0; m < 4; ++m) {
        int row = wr * 64 + m * 16 + rrow;
        int chunk = (kk * 4 + koff) ^ kxor;
        af[m] = *reinterpret_cast<const bf16x8*>(&As[row * 64 + chunk * 8]);
      }
#pragma unroll
      for (int n = 0; n < 4; ++n) {
        int row = wc * 64 + n * 16 + rrow;
        int chunk = (kk * 4 + koff) ^ kxor;
        bfv[n] = *reinterpret_cast<const bf16x8*>(&Bs[row * 64 + chunk * 8]);
      }
#pragma unroll
      for (int m = 0; m < 4; ++m)
#pragma unroll
        for (int n = 0; n < 4; ++n)
          acc[m][n] = __builtin_amdgcn_mfma_f32_16x16x32_bf16(af[m], bfv[n], acc[m][n], 0, 0, 0);
    }
    __syncthreads();
  }

  const int r0 = (lane >> 4) * 4;
  const int ccol = lane & 15;
#pragma unroll
  for (int m = 0; m < 4; ++m) {
#pragma unroll
    for (int n = 0; n < 4; ++n) {
      int col = n0 + wc * 64 + n * 16 + ccol;
#pragma unroll
      for (int i = 0; i < 4; ++i) {
        int t = m0 + wr * 64 + m * 16 + r0 + i;
        float v = acc[m][n][i];
        if (MODE == 0) {
          int j = jbase + col;
          float bias = (j < JEXP) ? bias_a[j] : bias_b[j - JEXP];
          float val = v + bias;
          float g = 0.5f * val * (1.0f + erff(val * 0.70710678118654752f));
          float wg = (j < JEXP) ? rw[(size_t)t * NEXP + (j >> 10)] : 1.0f;
          hOut[(size_t)t * jc + col] = f2bf(g * wg);
        } else if (MODE == 1) {
          float bias = 0.1f * bias_b[col];
#pragma unroll
          for (int e = 0; e < NEXP; ++e)
            bias += rw[(size_t)t * NEXP + e] * bias_a[(size_t)e * DIM + col];
          out[(size_t)t * DIM + col] = v + bias;
        } else {
          out[(size_t)t * DIM + col] += v;
        }
      }
    }
  }
}

extern "C" void kernel_launch(void* const* d_in, const int* in_sizes, int n_in,
                              void* d_out, int out_size, void* d_ws, size_t ws_size,
                              hipStream_t stream) {
  const float* x   = (const float*)d_in[0];
  const float* Wr  = (const float*)d_in[1];
  const float* br  = (const float*)d_in[2];
  const float* W1  = (const float*)d_in[3];
  const float* b1  = (const float*)d_in[4];
  const float* W2  = (const float*)d_in[5];
  const float* b2  = (const float*)d_in[6];
  const float* Ws1 = (const float*)d_in[7];
  const float* bs1 = (const float*)d_in[8];
  const float* Ws2 = (const float*)d_in[9];
  const float* bs2 = (const float*)d_in[10];
  float* out = (float*)d_out;

  char* wsb = (char*)d_ws;
  short* xb   = (short*)wsb;                       // 32 MiB
  float* rw   = (float*)(wsb + 33554432);          // 1 MiB region
  float* auxs = (float*)(wsb + 33816576);
  const size_t need_fixed = 33816832ull;

  // chunk width over the 9216 concat-hidden axis; multiple of 256
  const int jcands[8] = {9216, 4608, 3072, 2304, 1536, 768, 512, 256};
  int jc = 256;
  for (int ci = 0; ci < 8; ++ci) {
    if (need_fixed + (size_t)jcands[ci] * 24576ull <= ws_size) { jc = jcands[ci]; break; }
  }
  const int nc = JTOT / jc;
  short* w1t  = (short*)(wsb + need_fixed);
  short* w2t  = w1t + (size_t)jc * DIM;
  short* hbuf = w2t + (size_t)DIM * jc;

  // enable 128 KiB dynamic LDS for the big-tile GEMM; fall back if refused
  bool big = true;
  {
    auto* f0 = gemm256<0>; auto* f1 = gemm256<1>; auto* f2 = gemm256<2>;
    if (hipFuncSetAttribute(reinterpret_cast<const void*>(f0),
                            hipFuncAttributeMaxDynamicSharedMemorySize, 131072) != hipSuccess) big = false;
    if (hipFuncSetAttribute(reinterpret_cast<const void*>(f1),
                            hipFuncAttributeMaxDynamicSharedMemorySize, 131072) != hipSuccess) big = false;
    if (hipFuncSetAttribute(reinterpret_cast<const void*>(f2),
                            hipFuncAttributeMaxDynamicSharedMemorySize, 131072) != hipSuccess) big = false;
  }

  zero_aux_k<<<1, 64, 0, stream>>>(auxs);
  conv_x_k<<<(NTOK * DIM / 8) / 256, 256, 0, stream>>>(x, xb);
  router_k<<<NTOK / 4, 256, 0, stream>>>(x, Wr, br, rw, auxs);
  fin_aux_k<<<1, 64, 0, stream>>>(auxs, out + (size_t)NTOK * DIM);

  for (int c = 0; c < nc; ++c) {
    const int jbase = c * jc;
    conv_w1_k<<<dim3(jc / 64, DIM / 64), 256, 0, stream>>>(W1, Ws1, w1t, jbase, jc);
    conv_w2_k<<<dim3(jc / 64, DIM / 64), 256, 0, stream>>>(W2, Ws2, w2t, jbase, jc);
    if (big) {
      const int nx1 = jc / 256, ny = NTOK / 256;
      gemm256<0><<<nx1 * ny, 512, 131072, stream>>>(
          xb, w1t, DIM, rw, b1, bs1, hbuf, jbase, jc, nullptr, nx1);
      const int nx2 = DIM / 256;
      if (c == 0) {
        gemm256<1><<<nx2 * ny, 512, 131072, stream>>>(
            hbuf, w2t, jc, rw, b2, bs2, nullptr, 0, jc, out, nx2);
      } else {
        gemm256<2><<<nx2 * ny, 512, 131072, stream>>>(
            hbuf, w2t, jc, rw, nullptr, nullptr, nullptr, 0, jc, out, nx2);
      }
    } else {
      gemm128<0><<<dim3(jc / 128, NTOK / 128), 256, 0, stream>>>(
          xb, w1t, DIM, rw, b1, bs1, hbuf, jbase, jc, nullptr);
      if (c == 0) {
        gemm128<1><<<dim3(DIM / 128, NTOK / 128), 256, 0, stream>>>(
            hbuf, w2t, jc, rw, b2, bs2, nullptr, 0, jc, out);
      } else {
        gemm128<2><<<dim3(DIM / 128, NTOK / 128), 256, 0, stream>>>(
            hbuf, w2t, jc, rw, nullptr, nullptr, nullptr, 0, jc, out);
      }
    }
  }
}